// Round 4
// baseline (307.418 us; speedup 1.0000x reference)
//
#include <hip/hip_runtime.h>
#include <math.h>

#define HID 2048
#define NH 32
#define NKV 8
#define HD 64
#define BB 2
#define SS 2048
#define MTOT (BB * SS) // 4096

typedef __bf16 bf16;
typedef __bf16 bf16x8 __attribute__((ext_vector_type(8)));
typedef __bf16 bf16x4 __attribute__((ext_vector_type(4)));
typedef float f32x4 __attribute__((ext_vector_type(4)));

#define MFMA16(a, b, c) __builtin_amdgcn_mfma_f32_16x16x32_bf16((a), (b), (c), 0, 0, 0)

__device__ __forceinline__ void load_lds16(const void* g, void* l) {
  __builtin_amdgcn_global_load_lds((const __attribute__((address_space(1))) void*)g,
                                   (__attribute__((address_space(3))) void*)l, 16, 0, 0);
}

#define FENCE() asm volatile("" ::: "memory")
// Tile-top sync: counted vmcnt (never 0 in main loop) + lgkmcnt(0) so this
// wave's ds_reads have COMPLETED before it enters the barrier (orders them
// against other waves' post-barrier global_load_lds writebacks), then barrier.
#define SYNC_VM(N) do { FENCE(); \
  asm volatile("s_waitcnt vmcnt(" #N ") lgkmcnt(0)" ::: "memory"); \
  __builtin_amdgcn_s_barrier(); FENCE(); } while (0)

// ---------------- fused fp32 -> bf16 convert (all 5 tensors, one launch) ----------------
__global__ void cvt_all(const float* __restrict__ hs, const float* __restrict__ Wq,
                        const float* __restrict__ Wk, const float* __restrict__ Wv,
                        const float* __restrict__ Wo,
                        bf16* __restrict__ A_b, bf16* __restrict__ Wq_b,
                        bf16* __restrict__ Wk_b, bf16* __restrict__ Wv_b,
                        bf16* __restrict__ Wo_b) {
  int bid = blockIdx.x;
  const float* src;
  bf16* dst;
  if (bid < 8192)       { src = hs; dst = A_b; }
  else if (bid < 12288) { src = Wq; dst = Wq_b; bid -= 8192; }
  else if (bid < 13312) { src = Wk; dst = Wk_b; bid -= 12288; }
  else if (bid < 14336) { src = Wv; dst = Wv_b; bid -= 13312; }
  else                  { src = Wo; dst = Wo_b; bid -= 14336; }
  int i = (bid * 256 + threadIdx.x) * 4;
  float4 v = *(const float4*)(src + i);
  bf16x4 o;
  o[0] = (bf16)v.x; o[1] = (bf16)v.y; o[2] = (bf16)v.z; o[3] = (bf16)v.w;
  *(bf16x4*)(dst + i) = o;
}

// ---------------- pipelined GEMM core: C = A * W^T, K = 2048, 256x128 tile ----------------
// 512 threads = 8 waves (4M x 2N); per-wave output 64x64 (the round-2-verified
// no-spill body: acc[4][4], 8 ds_read_b128 + 16 MFMA per BK=32 tile). Per
// K-tile the block computes 2.1 MFLOP from one 24 KB staged tile -- 2x the
// work per sync round of the 128^2 version, amortizing the fixed barrier/
// latency cost that capped MfmaUtil at 27%. 72 KB LDS -> 2 WG/CU (16 waves)
// so cross-workgroup overlap hides the residual barrier stall (m114).
// THREE rotating LDS buffers: while computing tile kt (buf kt%3) stage tile
// kt+2; SYNC_VM(3) at tile top waits for all but tile kt+1's 3 loads --
// counted vmcnt, never drained to 0 in the main loop (T3+T4).
// LDS swizzle (T2, verified rounds 1-2: conflicts -> 0): logical row R
// (64 B = 4 chunks of 16 B) stored at byte p*128 + cg*16, p = R>>1,
// cg = (((R&1)<<2)|c) ^ (p&7). Inverse applied on the GLOBAL source address
// for staging (global_load_lds dest must stay linear), same XOR on ds_read.
__device__ __forceinline__ void gemm_core256x128(const char* Agc, const char* Bgc,
                                                 char* lds, f32x4 (&acc)[4][4]) {
  constexpr int ABYTES = 16384;     // A tile bytes (256 x 32 bf16)
  constexpr int BUFB = 24576;       // + B tile (128 x 32 bf16)
  constexpr int NT = HID / 32;      // 64 K-tiles

  const int tid = threadIdx.x;
  const int w = tid >> 6, lane = tid & 63;
  const int l16 = lane & 15, quad = lane >> 4;
  const int wr = w >> 1, wc = w & 1;
  const int wb = w * 1024;          // wave-uniform LDS staging base

  // staging: thread t owns LDS 16B-slot t (A also slot t+512 at +8192 B);
  // invert the swizzle to get the global (row, chunk) it must fetch. Slot
  // t+512 has p' = p+64 (p'&7 == p&7), so its source is srcR0 + 128 rows.
  const int cu = (tid & 7) ^ ((tid >> 3) & 7);
  const int srcR0 = 2 * (tid >> 3) + (cu >> 2);   // 0..127
  const int srcC = (cu & 3) * 16;
  const char* gA = Agc + (size_t)srcR0 * (HID * 2) + srcC;
  const char* gB = Bgc + (size_t)srcR0 * (HID * 2) + srcC;

  // ds_read offsets: fragment mi/ni at base + idx*1024 (16 rows = 8 pairs)
  const int acg16 = ((((l16 & 1) << 2) | quad) ^ ((l16 >> 1) & 7)) * 16;
  const int aoff = (wr * 32 + (l16 >> 1)) * 128 + acg16;
  const int boff = ABYTES + (wc * 32 + (l16 >> 1)) * 128 + acg16;

  // prologue: stage tiles 0 and 1 (3 loads per tile per thread: 2 A + 1 B)
#pragma unroll
  for (int t0 = 0; t0 < 2; ++t0) {
    char* lb = lds + t0 * BUFB;
    load_lds16(gA + t0 * 64, lb + wb);
    load_lds16(gA + (size_t)128 * (HID * 2) + t0 * 64, lb + 8192 + wb);
    load_lds16(gB + t0 * 64, lb + ABYTES + wb);
  }

  char* cur = lds;
  char* stg = lds + 2 * BUFB;
  for (int kt = 0; kt < NT; ++kt) {
    // all but the newest 3 loads (tile kt+1's) complete -> tile kt resident;
    // lgkmcnt(0)+barrier also makes it safe to overwrite buf (kt+2)%3, which
    // every wave finished reading during iteration kt-1.
    SYNC_VM(3);
    // tail clamp: re-stage tile NT-1 into a buffer that is never read.
    const int ks = (kt + 2 < NT) ? (kt + 2) * 64 : (NT - 1) * 64;

    // issue async stage of tile kt+2 (stays in flight across next barrier)
    load_lds16(gA + ks, stg + wb);
    load_lds16(gA + (size_t)128 * (HID * 2) + ks, stg + 8192 + wb);
    load_lds16(gB + ks, stg + ABYTES + wb);
    FENCE();  // pin stage-issue before the ds_reads

    bf16x8 af[4], bfr[4];
#pragma unroll
    for (int ni = 0; ni < 4; ++ni)
      bfr[ni] = *(const bf16x8*)(cur + boff + ni * 1024);
#pragma unroll
    for (int mi = 0; mi < 4; ++mi)
      af[mi] = *(const bf16x8*)(cur + aoff + mi * 1024);
    __builtin_amdgcn_s_setprio(1);
#pragma unroll
    for (int mi = 0; mi < 4; ++mi)
#pragma unroll
      for (int ni = 0; ni < 4; ++ni)
        acc[mi][ni] = MFMA16(af[mi], bfr[ni], acc[mi][ni]);
    __builtin_amdgcn_s_setprio(0);

    cur = (cur == lds + 2 * BUFB) ? lds : cur + BUFB;
    stg = (stg == lds + 2 * BUFB) ? lds : stg + BUFB;
  }
  // drain stray (clamped) stage loads before workgroup exit (LDS dealloc!).
  asm volatile("s_waitcnt vmcnt(0)" ::: "memory");
}

// ---------------- fused QKV projection + RoPE epilogue ----------------
#define QSCALE 0.1803368801f
#define L2B 0.4152410118f  // log2(10000)/32
__global__ __launch_bounds__(512, 4) void gemm_qkv(const bf16* __restrict__ A,
                                                   const bf16* __restrict__ Wq,
                                                   const bf16* __restrict__ Wk,
                                                   const bf16* __restrict__ Wv,
                                                   bf16* __restrict__ Qb,
                                                   bf16* __restrict__ Kb,
                                                   bf16* __restrict__ Vt) {
  __shared__ __align__(16) char lds[3 * 24576];  // 72 KB -> 2 WG/CU
  const int tileM = blockIdx.x * 256;
  const int n0 = blockIdx.y * 128;
  // mode boundaries (2048, 2560) are 128-aligned so each tile is pure-mode.
  const bf16* Wp;
  int mode;
  if (n0 < HID) { Wp = Wq + (size_t)n0 * HID; mode = 0; }
  else if (n0 < HID + 512) { Wp = Wk + (size_t)(n0 - HID) * HID; mode = 1; }
  else { Wp = Wv + (size_t)(n0 - HID - 512) * HID; mode = 2; }

  f32x4 acc[4][4];
#pragma unroll
  for (int i = 0; i < 4; ++i)
#pragma unroll
    for (int j = 0; j < 4; ++j) acc[i][j] = (f32x4){0.f, 0.f, 0.f, 0.f};

  gemm_core256x128((const char*)(A + (size_t)tileM * HID), (const char*)Wp, lds, acc);

  const int tid = threadIdx.x;
  const int w = tid >> 6, lane = tid & 63;
  const int l16 = lane & 15, quad = lane >> 4;
  const int wr = w >> 1, wc = w & 1;
  const int mbase = tileM + wr * 64;
  const int cb = n0 + wc * 64;  // 64-aligned -> wave col span = one head

  if (mode == 2) {
    // V: transposed layout [b,kvh,d,s]
#pragma unroll
    for (int mi = 0; mi < 4; ++mi)
#pragma unroll
      for (int ni = 0; ni < 4; ++ni)
#pragma unroll
        for (int r = 0; r < 4; ++r) {
          int grow = mbase + mi * 16 + quad * 4 + r;
          int b = grow >> 11, spos = grow & (SS - 1);
          int nv = cb + ni * 16 + l16 - (HID + 512);
          Vt[(((size_t)(b * NKV + (nv >> 6))) * HD + (nv & 63)) * SS + spos] =
              (bf16)acc[mi][ni][r];
        }
  } else {
    // Q or K: RoPE in fp32 regs. In-head col of ni is i = ni*16 + l16, so
    // pairs are (ni=0,ni=2) at freq idx l16 and (ni=1,ni=3) at l16+16.
    const float inv0 = __builtin_amdgcn_exp2f(-(float)l16 * L2B);
    const float inv1 = __builtin_amdgcn_exp2f(-(float)(l16 + 16) * L2B);
#pragma unroll
    for (int mi = 0; mi < 4; ++mi) {
#pragma unroll
      for (int r = 0; r < 4; ++r) {
        int grow = mbase + mi * 16 + quad * 4 + r;
        int b = grow >> 11, spos = grow & (SS - 1);
        float sn0, cs0, sn1, cs1;
        sincosf((float)spos * inv0, &sn0, &cs0);
        sincosf((float)spos * inv1, &sn1, &cs1);
        float a0 = acc[mi][0][r], a1 = acc[mi][1][r];
        float a2 = acc[mi][2][r], a3 = acc[mi][3][r];
        float o0 = a0 * cs0 - a2 * sn0;
        float o2 = a2 * cs0 + a0 * sn0;
        float o1 = a1 * cs1 - a3 * sn1;
        float o3 = a3 * cs1 + a1 * sn1;
        if (mode == 0) {
          bf16* qp = Qb + (size_t)grow * HID + cb + l16;
          qp[0]  = (bf16)(o0 * QSCALE);
          qp[16] = (bf16)(o1 * QSCALE);
          qp[32] = (bf16)(o2 * QSCALE);
          qp[48] = (bf16)(o3 * QSCALE);
        } else {
          int kvh = (cb - HID) >> 6;
          bf16* kp = Kb + ((size_t)(b * NKV + kvh) * SS + spos) * HD + l16;
          kp[0]  = (bf16)o0;
          kp[16] = (bf16)o1;
          kp[32] = (bf16)o2;
          kp[48] = (bf16)o3;
        }
      }
    }
  }
}

// ---------------- output projection (grid 16x16 = 256 blocks = 1/CU) ----------------
__global__ __launch_bounds__(512, 4) void gemm_out(const bf16* __restrict__ A,
                                                   const bf16* __restrict__ Wo,
                                                   float* __restrict__ out) {
  __shared__ __align__(16) char lds[3 * 24576];
  const int tileM = blockIdx.x * 256;
  const int n0 = blockIdx.y * 128;
  f32x4 acc[4][4];
#pragma unroll
  for (int i = 0; i < 4; ++i)
#pragma unroll
    for (int j = 0; j < 4; ++j) acc[i][j] = (f32x4){0.f, 0.f, 0.f, 0.f};

  gemm_core256x128((const char*)(A + (size_t)tileM * HID),
                   (const char*)(Wo + (size_t)n0 * HID), lds, acc);

  const int tid = threadIdx.x;
  const int w = tid >> 6, lane = tid & 63;
  const int l16 = lane & 15, quad = lane >> 4;
  const int wr = w >> 1, wc = w & 1;
#pragma unroll
  for (int mi = 0; mi < 4; ++mi)
#pragma unroll
    for (int ni = 0; ni < 4; ++ni)
#pragma unroll
      for (int r = 0; r < 4; ++r) {
        int grow = tileM + wr * 64 + mi * 16 + quad * 4 + r;
        int gcol = n0 + wc * 64 + ni * 16 + l16;
        out[(size_t)grow * HID + gcol] = acc[mi][ni][r];
      }
}

// ---------------- flash attention v5: block-cooperative LDS staging ----------------
#define PSTR 72
__global__ __launch_bounds__(256, 3) void attn(const bf16* __restrict__ Qb,
                                               const bf16* __restrict__ Kb,
                                               const bf16* __restrict__ Vt,
                                               bf16* __restrict__ Ctx) {
  __shared__ bf16 Ktile[2][64 * 64];
  __shared__ bf16 Vtile[2][64 * 64];
  __shared__ bf16 Pbuf[4][16 * PSTR];
  const int tid = threadIdx.x;
  const int w = tid >> 6, lane = tid & 63;
  const int l16 = lane & 15, quad = lane >> 4;
  const int bh = blockIdx.y, b = bh >> 5, h = bh & 31, kvh = h >> 2;
  bf16* Pw = &Pbuf[w][0];
  const char* Kslice = (const char*)(Kb + ((size_t)(b * NKV + kvh)) * SS * HD);
  const char* Vslice = (const char*)(Vt + ((size_t)(b * NKV + kvh)) * HD * SS);
  const int qrel = w * 16 + l16;

  const int srow = (lane >> 3) & 7;
  const int pchunk = ((lane & 7) ^ srow) << 4;
  const int so = ((quad ^ (l16 & 7)) << 4);
  const int so2 = so ^ 64;

  const int qtA = (int)blockIdx.x;

  int cur = 0;
  {
#pragma unroll
    for (int i = 0; i < 2; ++i) {
      const int r = w * 16 + i * 8 + srow;
      load_lds16(Kslice + (size_t)r * 128 + pchunk,
                 (char*)Ktile[0] + (w * 16 + i * 8) * 128);
      load_lds16(Vslice + (size_t)r * 4096 + pchunk,
                 (char*)Vtile[0] + (w * 16 + i * 8) * 128);
    }
  }

  for (int t = 0; t < 2; ++t) {
    const int qt = t ? (31 - qtA) : qtA;
    const int q = qt * 64 + qrel;

    const bf16* Qp = Qb + ((size_t)(b * SS + q)) * HID + h * HD + quad * 8;
    bf16x8 qb0 = *(const bf16x8*)Qp;
    bf16x8 qb1 = *(const bf16x8*)(Qp + 32);

    float l = 0.f;
    f32x4 oacc[4];
#pragma unroll
    for (int d = 0; d < 4; ++d) oacc[d] = (f32x4){0.f, 0.f, 0.f, 0.f};

    for (int kt = 0; kt <= qt; ++kt) {
      __syncthreads();

      const bool have_next = (kt < qt) || (t == 0);
      if (have_next) {
        const int nkb = (kt < qt) ? (kt + 1) * 64 : 0;
        const int nb = cur ^ 1;
#pragma unroll
        for (int i = 0; i < 2; ++i) {
          const int r = w * 16 + i * 8 + srow;
          load_lds16(Kslice + (size_t)(nkb + r) * 128 + pchunk,
                     (char*)Ktile[nb] + (w * 16 + i * 8) * 128);
          load_lds16(Vslice + (size_t)r * 4096 + (size_t)nkb * 2 + pchunk,
                     (char*)Vtile[nb] + (w * 16 + i * 8) * 128);
        }
      }

      const char* Kc = (const char*)Ktile[cur] + l16 * 128;
      const char* Vc = (const char*)Vtile[cur] + l16 * 128;
      const bool diag = (kt == qt);

#pragma unroll
      for (int nt = 0; nt < 4; ++nt) {
        bf16x8 kf0 = *(const bf16x8*)(Kc + nt * 2048 + so);
        bf16x8 kf1 = *(const bf16x8*)(Kc + nt * 2048 + so2);
        f32x4 s = {0.f, 0.f, 0.f, 0.f};
        s = MFMA16(kf0, qb0, s);
        s = MFMA16(kf1, qb1, s);
        bf16x4 pk;
        if (diag) {
          const int krel = nt * 16 + quad * 4;
#pragma unroll
          for (int r = 0; r < 4; ++r) {
            float p = (krel + r > qrel) ? 0.f : __builtin_amdgcn_exp2f(s[r]);
            l += p;
            pk[r] = (bf16)p;
          }
        } else {
#pragma unroll
          for (int r = 0; r < 4; ++r) {
            float p = __builtin_amdgcn_exp2f(s[r]);
            l += p;
            pk[r] = (bf16)p;
          }
        }
        *(bf16x4*)&Pw[l16 * PSTR + nt * 16 + quad * 4] = pk;
      }

      bf16x8 p0 = *(const bf16x8*)&Pw[l16 * PSTR + quad * 8];
      bf16x8 p1 = *(const bf16x8*)&Pw[l16 * PSTR + 32 + quad * 8];
#pragma unroll
      for (int dn = 0; dn < 4; ++dn) {
        bf16x8 v0 = *(const bf16x8*)(Vc + dn * 2048 + so);
        bf16x8 v1 = *(const bf16x8*)(Vc + dn * 2048 + so2);
        oacc[dn] = MFMA16(v0, p0, oacc[dn]);
        oacc[dn] = MFMA16(v1, p1, oacc[dn]);
      }
      cur ^= 1;
    }

    l += __shfl_xor(l, 16);
    l += __shfl_xor(l, 32);
    const float inv = 1.0f / l;
    bf16* Cp = Ctx + ((size_t)(b * SS + q)) * HID + h * HD + quad * 4;
#pragma unroll
    for (int dn = 0; dn < 4; ++dn) {
      bf16x4 ov;
#pragma unroll
      for (int r = 0; r < 4; ++r) ov[r] = (bf16)(oacc[dn][r] * inv);
      *(bf16x4*)(Cp + dn * 16) = ov;
    }
  }
}

// ---------------- launch ----------------
extern "C" void kernel_launch(void* const* d_in, const int* in_sizes, int n_in,
                              void* d_out, int out_size, void* d_ws, size_t ws_size,
                              hipStream_t stream) {
  const float* hs = (const float*)d_in[0];
  const float* Wq = (const float*)d_in[2];
  const float* Wk = (const float*)d_in[3];
  const float* Wv = (const float*)d_in[4];
  const float* Wo = (const float*)d_in[5];

  char* ws = (char*)d_ws;
  bf16* A_b  = (bf16*)(ws);              // 16 MB ; reused as Ctx after QKV gemm
  bf16* Wq_b = (bf16*)(ws + 16777216);   // 8 MB
  bf16* Wk_b = (bf16*)(ws + 25165824);   // 2 MB
  bf16* Wv_b = (bf16*)(ws + 27262976);   // 2 MB
  bf16* Wo_b = (bf16*)(ws + 29360128);   // 8 MB
  bf16* Qb   = (bf16*)(ws + 37748736);   // 16 MB
  bf16* Kb   = (bf16*)(ws + 54525952);   // 4 MB
  bf16* Vt   = (bf16*)(ws + 58720256);   // 4 MB  (end: 62914560)
  bf16* Ctx  = A_b;

  cvt_all<<<18432, 256, 0, stream>>>(hs, Wq, Wk, Wv, Wo, A_b, Wq_b, Wk_b, Wv_b, Wo_b);
  gemm_qkv<<<dim3(MTOT / 256, 24), 512, 0, stream>>>(A_b, Wq_b, Wk_b, Wv_b, Qb, Kb, Vt);
  attn<<<dim3(16, BB * NH), 256, 0, stream>>>(Qb, Kb, Vt, Ctx);
  gemm_out<<<dim3(MTOT / 256, HID / 128), 512, 0, stream>>>(Ctx, Wo_b, (float*)d_out);
}

// Round 5
// 298.509 us; speedup vs baseline: 1.0298x; 1.0298x over previous
//
#include <hip/hip_runtime.h>
#include <math.h>

#define HID 2048
#define NH 32
#define NKV 8
#define HD 64
#define BB 2
#define SS 2048
#define MTOT (BB * SS) // 4096

typedef __bf16 bf16;
typedef __bf16 bf16x8 __attribute__((ext_vector_type(8)));
typedef __bf16 bf16x4 __attribute__((ext_vector_type(4)));
typedef float f32x4 __attribute__((ext_vector_type(4)));

#define MFMA16(a, b, c) __builtin_amdgcn_mfma_f32_16x16x32_bf16((a), (b), (c), 0, 0, 0)

__device__ __forceinline__ void load_lds16(const void* g, void* l) {
  __builtin_amdgcn_global_load_lds((const __attribute__((address_space(1))) void*)g,
                                   (__attribute__((address_space(3))) void*)l, 16, 0, 0);
}

#define FENCE() asm volatile("" ::: "memory")
// Tile-top sync: counted vmcnt (never 0 in main loop) + lgkmcnt(0) so this
// wave's ds_reads have COMPLETED before it enters the barrier (orders them
// against other waves' post-barrier global_load_lds writebacks), then barrier.
#define SYNC_VM(N) do { FENCE(); \
  asm volatile("s_waitcnt vmcnt(" #N ") lgkmcnt(0)" ::: "memory"); \
  __builtin_amdgcn_s_barrier(); FENCE(); } while (0)

// ---------------- fused fp32 -> bf16 convert (all 5 tensors, one launch) ----------------
__global__ void cvt_all(const float* __restrict__ hs, const float* __restrict__ Wq,
                        const float* __restrict__ Wk, const float* __restrict__ Wv,
                        const float* __restrict__ Wo,
                        bf16* __restrict__ A_b, bf16* __restrict__ Wq_b,
                        bf16* __restrict__ Wk_b, bf16* __restrict__ Wv_b,
                        bf16* __restrict__ Wo_b) {
  int bid = blockIdx.x;
  const float* src;
  bf16* dst;
  if (bid < 8192)       { src = hs; dst = A_b; }
  else if (bid < 12288) { src = Wq; dst = Wq_b; bid -= 8192; }
  else if (bid < 13312) { src = Wk; dst = Wk_b; bid -= 12288; }
  else if (bid < 14336) { src = Wv; dst = Wv_b; bid -= 13312; }
  else                  { src = Wo; dst = Wo_b; bid -= 14336; }
  int i = (bid * 256 + threadIdx.x) * 4;
  float4 v = *(const float4*)(src + i);
  bf16x4 o;
  o[0] = (bf16)v.x; o[1] = (bf16)v.y; o[2] = (bf16)v.z; o[3] = (bf16)v.w;
  *(bf16x4*)(dst + i) = o;
}

// ---------------- pipelined GEMM core: C = A * W^T, K = 2048, 256x128 tile ----------------
// (verified round 4; see round-4 notes. 8 waves, 3 rotating buffers, counted
// SYNC_VM(3), T2 swizzle with conflicts == 0.)
__device__ __forceinline__ void gemm_core256x128(const char* Agc, const char* Bgc,
                                                 char* lds, f32x4 (&acc)[4][4]) {
  constexpr int ABYTES = 16384;     // A tile bytes (256 x 32 bf16)
  constexpr int BUFB = 24576;       // + B tile (128 x 32 bf16)
  constexpr int NT = HID / 32;      // 64 K-tiles

  const int tid = threadIdx.x;
  const int w = tid >> 6, lane = tid & 63;
  const int l16 = lane & 15, quad = lane >> 4;
  const int wr = w >> 1, wc = w & 1;
  const int wb = w * 1024;          // wave-uniform LDS staging base

  const int cu = (tid & 7) ^ ((tid >> 3) & 7);
  const int srcR0 = 2 * (tid >> 3) + (cu >> 2);   // 0..127
  const int srcC = (cu & 3) * 16;
  const char* gA = Agc + (size_t)srcR0 * (HID * 2) + srcC;
  const char* gB = Bgc + (size_t)srcR0 * (HID * 2) + srcC;

  const int acg16 = ((((l16 & 1) << 2) | quad) ^ ((l16 >> 1) & 7)) * 16;
  const int aoff = (wr * 32 + (l16 >> 1)) * 128 + acg16;
  const int boff = ABYTES + (wc * 32 + (l16 >> 1)) * 128 + acg16;

#pragma unroll
  for (int t0 = 0; t0 < 2; ++t0) {
    char* lb = lds + t0 * BUFB;
    load_lds16(gA + t0 * 64, lb + wb);
    load_lds16(gA + (size_t)128 * (HID * 2) + t0 * 64, lb + 8192 + wb);
    load_lds16(gB + t0 * 64, lb + ABYTES + wb);
  }

  char* cur = lds;
  char* stg = lds + 2 * BUFB;
  for (int kt = 0; kt < NT; ++kt) {
    SYNC_VM(3);
    const int ks = (kt + 2 < NT) ? (kt + 2) * 64 : (NT - 1) * 64;

    load_lds16(gA + ks, stg + wb);
    load_lds16(gA + (size_t)128 * (HID * 2) + ks, stg + 8192 + wb);
    load_lds16(gB + ks, stg + ABYTES + wb);
    FENCE();

    bf16x8 af[4], bfr[4];
#pragma unroll
    for (int ni = 0; ni < 4; ++ni)
      bfr[ni] = *(const bf16x8*)(cur + boff + ni * 1024);
#pragma unroll
    for (int mi = 0; mi < 4; ++mi)
      af[mi] = *(const bf16x8*)(cur + aoff + mi * 1024);
    __builtin_amdgcn_s_setprio(1);
#pragma unroll
    for (int mi = 0; mi < 4; ++mi)
#pragma unroll
      for (int ni = 0; ni < 4; ++ni)
        acc[mi][ni] = MFMA16(af[mi], bfr[ni], acc[mi][ni]);
    __builtin_amdgcn_s_setprio(0);

    cur = (cur == lds + 2 * BUFB) ? lds : cur + BUFB;
    stg = (stg == lds + 2 * BUFB) ? lds : stg + BUFB;
  }
  asm volatile("s_waitcnt vmcnt(0)" ::: "memory");
}

// ---------------- fused QKV projection + RoPE epilogue ----------------
#define QSCALE 0.1803368801f
#define L2B 0.4152410118f  // log2(10000)/32
__global__ __launch_bounds__(512, 4) void gemm_qkv(const bf16* __restrict__ A,
                                                   const bf16* __restrict__ Wq,
                                                   const bf16* __restrict__ Wk,
                                                   const bf16* __restrict__ Wv,
                                                   bf16* __restrict__ Qb,
                                                   bf16* __restrict__ Kb,
                                                   bf16* __restrict__ Vt) {
  __shared__ __align__(16) char lds[3 * 24576];  // 72 KB -> 2 WG/CU
  const int tileM = blockIdx.x * 256;
  const int n0 = blockIdx.y * 128;
  const bf16* Wp;
  int mode;
  if (n0 < HID) { Wp = Wq + (size_t)n0 * HID; mode = 0; }
  else if (n0 < HID + 512) { Wp = Wk + (size_t)(n0 - HID) * HID; mode = 1; }
  else { Wp = Wv + (size_t)(n0 - HID - 512) * HID; mode = 2; }

  f32x4 acc[4][4];
#pragma unroll
  for (int i = 0; i < 4; ++i)
#pragma unroll
    for (int j = 0; j < 4; ++j) acc[i][j] = (f32x4){0.f, 0.f, 0.f, 0.f};

  gemm_core256x128((const char*)(A + (size_t)tileM * HID), (const char*)Wp, lds, acc);

  const int tid = threadIdx.x;
  const int w = tid >> 6, lane = tid & 63;
  const int l16 = lane & 15, quad = lane >> 4;
  const int wr = w >> 1, wc = w & 1;
  const int mbase = tileM + wr * 64;
  const int cb = n0 + wc * 64;  // 64-aligned -> wave col span = one head

  if (mode == 2) {
    // V: transposed layout [b,kvh,d,s]
#pragma unroll
    for (int mi = 0; mi < 4; ++mi)
#pragma unroll
      for (int ni = 0; ni < 4; ++ni)
#pragma unroll
        for (int r = 0; r < 4; ++r) {
          int grow = mbase + mi * 16 + quad * 4 + r;
          int b = grow >> 11, spos = grow & (SS - 1);
          int nv = cb + ni * 16 + l16 - (HID + 512);
          Vt[(((size_t)(b * NKV + (nv >> 6))) * HD + (nv & 63)) * SS + spos] =
              (bf16)acc[mi][ni][r];
        }
  } else {
    // Q or K: RoPE in fp32 regs; pairs (ni=0,ni=2) at freq l16, (1,3) at l16+16.
    const float inv0 = __builtin_amdgcn_exp2f(-(float)l16 * L2B);
    const float inv1 = __builtin_amdgcn_exp2f(-(float)(l16 + 16) * L2B);
#pragma unroll
    for (int mi = 0; mi < 4; ++mi) {
#pragma unroll
      for (int r = 0; r < 4; ++r) {
        int grow = mbase + mi * 16 + quad * 4 + r;
        int b = grow >> 11, spos = grow & (SS - 1);
        float sn0, cs0, sn1, cs1;
        sincosf((float)spos * inv0, &sn0, &cs0);
        sincosf((float)spos * inv1, &sn1, &cs1);
        float a0 = acc[mi][0][r], a1 = acc[mi][1][r];
        float a2 = acc[mi][2][r], a3 = acc[mi][3][r];
        float o0 = a0 * cs0 - a2 * sn0;
        float o2 = a2 * cs0 + a0 * sn0;
        float o1 = a1 * cs1 - a3 * sn1;
        float o3 = a3 * cs1 + a1 * sn1;
        if (mode == 0) {
          bf16* qp = Qb + (size_t)grow * HID + cb + l16;
          qp[0]  = (bf16)(o0 * QSCALE);
          qp[16] = (bf16)(o1 * QSCALE);
          qp[32] = (bf16)(o2 * QSCALE);
          qp[48] = (bf16)(o3 * QSCALE);
        } else {
          int kvh = (cb - HID) >> 6;
          bf16* kp = Kb + ((size_t)(b * NKV + kvh) * SS + spos) * HD + l16;
          kp[0]  = (bf16)o0;
          kp[16] = (bf16)o1;
          kp[32] = (bf16)o2;
          kp[48] = (bf16)o3;
        }
      }
    }
  }
}

// ---------------- output projection (grid 16x16 = 256 blocks) ----------------
__global__ __launch_bounds__(512, 4) void gemm_out(const bf16* __restrict__ A,
                                                   const bf16* __restrict__ Wo,
                                                   float* __restrict__ out) {
  __shared__ __align__(16) char lds[3 * 24576];
  const int tileM = blockIdx.x * 256;
  const int n0 = blockIdx.y * 128;
  f32x4 acc[4][4];
#pragma unroll
  for (int i = 0; i < 4; ++i)
#pragma unroll
    for (int j = 0; j < 4; ++j) acc[i][j] = (f32x4){0.f, 0.f, 0.f, 0.f};

  gemm_core256x128((const char*)(A + (size_t)tileM * HID),
                   (const char*)(Wo + (size_t)n0 * HID), lds, acc);

  const int tid = threadIdx.x;
  const int w = tid >> 6, lane = tid & 63;
  const int l16 = lane & 15, quad = lane >> 4;
  const int wr = w >> 1, wc = w & 1;
#pragma unroll
  for (int mi = 0; mi < 4; ++mi)
#pragma unroll
    for (int ni = 0; ni < 4; ++ni)
#pragma unroll
      for (int r = 0; r < 4; ++r) {
        int grow = tileM + wr * 64 + mi * 16 + quad * 4 + r;
        int gcol = n0 + wc * 64 + ni * 16 + l16;
        out[(size_t)grow * HID + gcol] = acc[mi][ni][r];
      }
}

// ---------------- flash attention v6: 128 q-rows per block (2 subtiles) ----------------
// grid (8, BB*NH) = 512 blocks = exactly 2/CU, uniform (no 1.33-round tail).
// Block x: pass 0 -> 128-row superblock X=x, pass 1 -> X=15-x; iterations
// (2x+2)+(2(15-x)+2) = 34 uniform. Each wave owns q-rows w*16+l16 (subtile A)
// and +64 (subtile B) of the superblock. K/V fragments are read from LDS once
// and feed BOTH subtiles' MFMAs: 32 MFMA per 16 K/V ds_reads, half the
// barriers/staging per FLOP vs v5. Diagonal: kt==2X masks A; kt==2X+1 skips A
// entirely (writes zero P) and masks B. Staging/swizzle identical to v5.
#define PSTR 72
__global__ __launch_bounds__(256, 3) void attn(const bf16* __restrict__ Qb,
                                               const bf16* __restrict__ Kb,
                                               const bf16* __restrict__ Vt,
                                               bf16* __restrict__ Ctx) {
  __shared__ bf16 Ktile[2][64 * 64];
  __shared__ bf16 Vtile[2][64 * 64];
  __shared__ bf16 Pbuf[4][32 * PSTR];   // per wave: rows 0-15 = A, 16-31 = B
  const int tid = threadIdx.x;
  const int w = tid >> 6, lane = tid & 63;
  const int l16 = lane & 15, quad = lane >> 4;
  const int bh = blockIdx.y, b = bh >> 5, h = bh & 31, kvh = h >> 2;
  bf16* Pw = &Pbuf[w][0];
  const char* Kslice = (const char*)(Kb + ((size_t)(b * NKV + kvh)) * SS * HD);
  const char* Vslice = (const char*)(Vt + ((size_t)(b * NKV + kvh)) * HD * SS);
  const int qrel = w * 16 + l16;        // 0..63 within each 64-row subtile

  const int srow = (lane >> 3) & 7;
  const int pchunk = ((lane & 7) ^ srow) << 4;
  const int so = ((quad ^ (l16 & 7)) << 4);
  const int so2 = so ^ 64;

  const int xA = (int)blockIdx.x;       // 0..7

  int cur = 0;
  // stage the very first K/V tile (kt=0)
  {
#pragma unroll
    for (int i = 0; i < 2; ++i) {
      const int r = w * 16 + i * 8 + srow;
      load_lds16(Kslice + (size_t)r * 128 + pchunk,
                 (char*)Ktile[0] + (w * 16 + i * 8) * 128);
      load_lds16(Vslice + (size_t)r * 4096 + pchunk,
                 (char*)Vtile[0] + (w * 16 + i * 8) * 128);
    }
  }

  for (int t = 0; t < 2; ++t) {
    const int X = t ? (15 - xA) : xA;   // 128-row superblock index
    const int qA = X * 128 + qrel;
    const int ktmax = 2 * X + 1;        // last kv tile (64 keys each)

    const bf16* QpA = Qb + ((size_t)(b * SS + qA)) * HID + h * HD + quad * 8;
    bf16x8 qa0 = *(const bf16x8*)QpA;
    bf16x8 qa1 = *(const bf16x8*)(QpA + 32);
    const bf16* QpB = QpA + (size_t)64 * HID;
    bf16x8 qbB0 = *(const bf16x8*)QpB;
    bf16x8 qbB1 = *(const bf16x8*)(QpB + 32);

    float lA = 0.f, lB = 0.f;
    f32x4 oA[4], oB[4];
#pragma unroll
    for (int d = 0; d < 4; ++d) {
      oA[d] = (f32x4){0.f, 0.f, 0.f, 0.f};
      oB[d] = (f32x4){0.f, 0.f, 0.f, 0.f};
    }

    for (int kt = 0; kt <= ktmax; ++kt) {
      __syncthreads();   // cur tile ready (staged a full compute phase ago)

      const bool have_next = (kt < ktmax) || (t == 0);
      if (have_next) {
        const int nkb = (kt < ktmax) ? (kt + 1) * 64 : 0;  // last: tile 0 for pass 1
        const int nb = cur ^ 1;
#pragma unroll
        for (int i = 0; i < 2; ++i) {
          const int r = w * 16 + i * 8 + srow;
          load_lds16(Kslice + (size_t)(nkb + r) * 128 + pchunk,
                     (char*)Ktile[nb] + (w * 16 + i * 8) * 128);
          load_lds16(Vslice + (size_t)r * 4096 + (size_t)nkb * 2 + pchunk,
                     (char*)Vtile[nb] + (w * 16 + i * 8) * 128);
        }
      }

      const char* Kc = (const char*)Ktile[cur] + l16 * 128;
      const char* Vc = (const char*)Vtile[cur] + l16 * 128;
      const bool skipA = (kt == ktmax);       // A fully masked on last tile
      const bool diagA = (kt == ktmax - 1);   // kt == 2X
      const bool diagB = (kt == ktmax);       // kt == 2X+1

      // QK^T + streaming no-max exp2 softmax for both subtiles; kf shared.
#pragma unroll
      for (int nt = 0; nt < 4; ++nt) {
        bf16x8 kf0 = *(const bf16x8*)(Kc + nt * 2048 + so);
        bf16x8 kf1 = *(const bf16x8*)(Kc + nt * 2048 + so2);
        const int krel = nt * 16 + quad * 4;

        bf16x4 pkA;
        if (skipA) {
          pkA[0] = (bf16)0.f; pkA[1] = (bf16)0.f;
          pkA[2] = (bf16)0.f; pkA[3] = (bf16)0.f;
        } else {
          f32x4 s = {0.f, 0.f, 0.f, 0.f};
          s = MFMA16(kf0, qa0, s);   // S^T: row = key, col = q (l16)
          s = MFMA16(kf1, qa1, s);
          if (diagA) {
#pragma unroll
            for (int r = 0; r < 4; ++r) {
              float p = (krel + r > qrel) ? 0.f : __builtin_amdgcn_exp2f(s[r]);
              lA += p;
              pkA[r] = (bf16)p;
            }
          } else {
#pragma unroll
            for (int r = 0; r < 4; ++r) {
              float p = __builtin_amdgcn_exp2f(s[r]);
              lA += p;
              pkA[r] = (bf16)p;
            }
          }
        }
        *(bf16x4*)&Pw[l16 * PSTR + krel] = pkA;

        f32x4 sB = {0.f, 0.f, 0.f, 0.f};
        sB = MFMA16(kf0, qbB0, sB);
        sB = MFMA16(kf1, qbB1, sB);
        bf16x4 pkB;
        if (diagB) {
#pragma unroll
          for (int r = 0; r < 4; ++r) {
            float p = (krel + r > qrel) ? 0.f : __builtin_amdgcn_exp2f(sB[r]);
            lB += p;
            pkB[r] = (bf16)p;
          }
        } else {
#pragma unroll
          for (int r = 0; r < 4; ++r) {
            float p = __builtin_amdgcn_exp2f(sB[r]);
            lB += p;
            pkB[r] = (bf16)p;
          }
        }
        *(bf16x4*)&Pw[(16 + l16) * PSTR + krel] = pkB;
      }

      // P back as B-operand fragments (per-wave buffer, no barrier needed)
      bf16x8 pA0 = *(const bf16x8*)&Pw[l16 * PSTR + quad * 8];
      bf16x8 pA1 = *(const bf16x8*)&Pw[l16 * PSTR + 32 + quad * 8];
      bf16x8 pB0 = *(const bf16x8*)&Pw[(16 + l16) * PSTR + quad * 8];
      bf16x8 pB1 = *(const bf16x8*)&Pw[(16 + l16) * PSTR + 32 + quad * 8];
#pragma unroll
      for (int dn = 0; dn < 4; ++dn) {
        bf16x8 v0 = *(const bf16x8*)(Vc + dn * 2048 + so);
        bf16x8 v1 = *(const bf16x8*)(Vc + dn * 2048 + so2);
        oA[dn] = MFMA16(v0, pA0, oA[dn]);  // O^T: row = d, col = q
        oA[dn] = MFMA16(v1, pA1, oA[dn]);
        oB[dn] = MFMA16(v0, pB0, oB[dn]);
        oB[dn] = MFMA16(v1, pB1, oB[dn]);
      }
      cur ^= 1;
    }

    lA += __shfl_xor(lA, 16);
    lA += __shfl_xor(lA, 32);
    lB += __shfl_xor(lB, 16);
    lB += __shfl_xor(lB, 32);
    const float invA = 1.0f / lA;
    const float invB = 1.0f / lB;
    bf16* CpA = Ctx + ((size_t)(b * SS + qA)) * HID + h * HD + quad * 4;
    bf16* CpB = CpA + (size_t)64 * HID;
#pragma unroll
    for (int dn = 0; dn < 4; ++dn) {
      bf16x4 ovA, ovB;
#pragma unroll
      for (int r = 0; r < 4; ++r) {
        ovA[r] = (bf16)(oA[dn][r] * invA);
        ovB[r] = (bf16)(oB[dn][r] * invB);
      }
      *(bf16x4*)(CpA + dn * 16) = ovA;
      *(bf16x4*)(CpB + dn * 16) = ovB;
    }
  }
}

// ---------------- launch ----------------
extern "C" void kernel_launch(void* const* d_in, const int* in_sizes, int n_in,
                              void* d_out, int out_size, void* d_ws, size_t ws_size,
                              hipStream_t stream) {
  const float* hs = (const float*)d_in[0];
  const float* Wq = (const float*)d_in[2];
  const float* Wk = (const float*)d_in[3];
  const float* Wv = (const float*)d_in[4];
  const float* Wo = (const float*)d_in[5];

  char* ws = (char*)d_ws;
  bf16* A_b  = (bf16*)(ws);              // 16 MB ; reused as Ctx after QKV gemm
  bf16* Wq_b = (bf16*)(ws + 16777216);   // 8 MB
  bf16* Wk_b = (bf16*)(ws + 25165824);   // 2 MB
  bf16* Wv_b = (bf16*)(ws + 27262976);   // 2 MB
  bf16* Wo_b = (bf16*)(ws + 29360128);   // 8 MB
  bf16* Qb   = (bf16*)(ws + 37748736);   // 16 MB
  bf16* Kb   = (bf16*)(ws + 54525952);   // 4 MB
  bf16* Vt   = (bf16*)(ws + 58720256);   // 4 MB  (end: 62914560)
  bf16* Ctx  = A_b;

  cvt_all<<<18432, 256, 0, stream>>>(hs, Wq, Wk, Wv, Wo, A_b, Wq_b, Wk_b, Wv_b, Wo_b);
  gemm_qkv<<<dim3(MTOT / 256, 24), 512, 0, stream>>>(A_b, Wq_b, Wk_b, Wv_b, Qb, Kb, Vt);
  attn<<<dim3(8, BB * NH), 256, 0, stream>>>(Qb, Kb, Vt, Ctx);
  gemm_out<<<dim3(MTOT / 256, HID / 128), 512, 0, stream>>>(Ctx, Wo_b, (float*)d_out);
}

// Round 6
// 296.692 us; speedup vs baseline: 1.0362x; 1.0061x over previous
//
#include <hip/hip_runtime.h>
#include <math.h>

#define HID 2048
#define NH 32
#define NKV 8
#define HD 64
#define BB 2
#define SS 2048
#define MTOT (BB * SS) // 4096

typedef __bf16 bf16;
typedef __bf16 bf16x8 __attribute__((ext_vector_type(8)));
typedef __bf16 bf16x4 __attribute__((ext_vector_type(4)));
typedef float f32x4 __attribute__((ext_vector_type(4)));

#define MFMA16(a, b, c) __builtin_amdgcn_mfma_f32_16x16x32_bf16((a), (b), (c), 0, 0, 0)

__device__ __forceinline__ void load_lds16(const void* g, void* l) {
  __builtin_amdgcn_global_load_lds((const __attribute__((address_space(1))) void*)g,
                                   (__attribute__((address_space(3))) void*)l, 16, 0, 0);
}

#define FENCE() asm volatile("" ::: "memory")
// Tile-top sync: counted vmcnt (never 0 in main loop) + lgkmcnt(0) so this
// wave's ds_reads have COMPLETED before it enters the barrier (orders them
// against other waves' post-barrier global_load_lds writebacks), then barrier.
#define SYNC_VM(N) do { FENCE(); \
  asm volatile("s_waitcnt vmcnt(" #N ") lgkmcnt(0)" ::: "memory"); \
  __builtin_amdgcn_s_barrier(); FENCE(); } while (0)

// ---------------- fused fp32 -> bf16 convert (all 5 tensors, one launch) ----------------
__global__ void cvt_all(const float* __restrict__ hs, const float* __restrict__ Wq,
                        const float* __restrict__ Wk, const float* __restrict__ Wv,
                        const float* __restrict__ Wo,
                        bf16* __restrict__ A_b, bf16* __restrict__ Wq_b,
                        bf16* __restrict__ Wk_b, bf16* __restrict__ Wv_b,
                        bf16* __restrict__ Wo_b) {
  int bid = blockIdx.x;
  const float* src;
  bf16* dst;
  if (bid < 8192)       { src = hs; dst = A_b; }
  else if (bid < 12288) { src = Wq; dst = Wq_b; bid -= 8192; }
  else if (bid < 13312) { src = Wk; dst = Wk_b; bid -= 12288; }
  else if (bid < 14336) { src = Wv; dst = Wv_b; bid -= 13312; }
  else                  { src = Wo; dst = Wo_b; bid -= 14336; }
  int i = (bid * 256 + threadIdx.x) * 4;
  float4 v = *(const float4*)(src + i);
  bf16x4 o;
  o[0] = (bf16)v.x; o[1] = (bf16)v.y; o[2] = (bf16)v.z; o[3] = (bf16)v.w;
  *(bf16x4*)(dst + i) = o;
}

// ---------------- pipelined GEMM core: C = A * W^T, K = 2048, 256x128 tile, BK = 64 ----------------
// 512 threads = 8 waves (4M x 2N); per-wave output 64x64 (acc[4][4], verified
// body). BK = 64 per K-step: 32 MFMA per wave per single barrier+vmcnt -- 2x
// the amortization of the BK=32 core that plateaued at ~980 TF/active-CU.
// Per-CU balance at 1 WG/CU: MFMA ~1036 cyc/iter vs LDS-read ~1000 cyc/iter
// (separate pipes, overlap) -- MFMA is the critical resource.
// LDS: per buffer A 256x64 bf16 (32 KB) + B 128x64 (16 KB) = 48 KB; THREE
// rotating buffers = 144 KB -> 1 WG/CU. Same verified invariants as the BK=32
// core: compute kt from buf kt%3, stage kt+2 into buf (kt+2)%3; SYNC_VM(6)
// at tile top waits all but tile kt+1's 6 loads (counted vmcnt, never 0 in
// the main loop); lgkmcnt(0)+barrier publishes all reads of buf (kt+2)%3
// (done in iteration kt-1) before any wave's stage lands there.
// LDS swizzle (T2, 8-chunk generalization of the verified 4-chunk one):
// logical row R (128 B = 8 chunks of 16 B) stored with chunk c at
// (c ^ (R&7)). A 16-lane column read touches 8 distinct chunks = 32 banks,
// 2 lanes/bank-line = free. Staging: linear LDS slot s (16 B) holds logical
// (row = s>>3, chunk = (s&7) ^ ((s>>3)&7)); inverse applied on the GLOBAL
// source address (global_load_lds dest must stay linear); same XOR on ds_read.
__device__ __forceinline__ void gemm_core_k64(const char* Agc, const char* Bgc,
                                              char* lds, f32x4 (&acc)[4][4]) {
  constexpr int ABYTES = 32768;   // A tile: 256 rows x 64 cols bf16
  constexpr int BUFB = 49152;     // + B tile: 128 rows x 64 cols bf16
  constexpr int NT = HID / 64;    // 32 K-steps

  const int tid = threadIdx.x;
  const int w = tid >> 6, lane = tid & 63;
  const int l16 = lane & 15, quad = lane >> 4;
  const int wr = w >> 1, wc = w & 1;
  const int wb = w * 1024;        // wave-uniform LDS staging base

  // staging: wave w, load j covers slots w*64 + j*512 + lane ->
  // row = w*8 + j*64 + (lane>>3), logical chunk = (lane&7) ^ ((lane>>3)&7).
  const int cu = (lane & 7) ^ ((lane >> 3) & 7);
  const char* gA = Agc + (size_t)(w * 8 + (lane >> 3)) * 4096 + cu * 16;
  const char* gB = Bgc + (size_t)(w * 8 + (lane >> 3)) * 4096 + cu * 16;

  // ds_read: frag (mi|ni, ks): base + (64*wrc + mi*16 + l16)*128 +
  // ((ks*4 + quad) ^ (l16&7))*16   (row&7 == l16&7 since 16|64 rows align)
  const int aswz = l16 & 7;
  const int a_k0 = ((0 + quad) ^ aswz) * 16;   // ks = 0
  const int a_k1 = ((4 + quad) ^ aswz) * 16;   // ks = 1
  const int arow = (wr * 64 + l16) * 128;
  const int brow = (wc * 64 + l16) * 128;

  // prologue: stage K-steps 0 and 1 (6 loads per wave per K-step: 4 A + 2 B)
#pragma unroll
  for (int t0 = 0; t0 < 2; ++t0) {
    char* lb = lds + t0 * BUFB;
#pragma unroll
    for (int j = 0; j < 4; ++j)
      load_lds16(gA + (size_t)j * (64 * 4096) + t0 * 128, lb + wb + j * 8192);
#pragma unroll
    for (int j = 0; j < 2; ++j)
      load_lds16(gB + (size_t)j * (64 * 4096) + t0 * 128, lb + ABYTES + wb + j * 8192);
  }

  char* cur = lds;
  char* stg = lds + 2 * BUFB;
  for (int kt = 0; kt < NT; ++kt) {
    // all but the newest 6 loads (K-step kt+1's) complete -> kt resident;
    // lgkmcnt(0)+barrier also publishes that buf (kt+2)%3 is fully read.
    SYNC_VM(6);
    // tail clamp: re-stage K-step NT-1 into a buffer that is never read.
    const int ks = (kt + 2 < NT) ? (kt + 2) : (NT - 1);
    const size_t ko = (size_t)ks * 128;

    // issue async stage of K-step kt+2 (stays in flight across next barrier)
#pragma unroll
    for (int j = 0; j < 4; ++j)
      load_lds16(gA + (size_t)j * (64 * 4096) + ko, stg + wb + j * 8192);
#pragma unroll
    for (int j = 0; j < 2; ++j)
      load_lds16(gB + (size_t)j * (64 * 4096) + ko, stg + ABYTES + wb + j * 8192);
    FENCE();  // pin stage-issue before the ds_reads

    const char* Ac = cur;
    const char* Bc = cur + ABYTES;
    bf16x8 af0[4], af1[4], bf0[4], bf1[4];
#pragma unroll
    for (int ni = 0; ni < 4; ++ni) {
      bf0[ni] = *(const bf16x8*)(Bc + brow + ni * 2048 + a_k0);
      bf1[ni] = *(const bf16x8*)(Bc + brow + ni * 2048 + a_k1);
    }
#pragma unroll
    for (int mi = 0; mi < 4; ++mi) {
      af0[mi] = *(const bf16x8*)(Ac + arow + mi * 2048 + a_k0);
      af1[mi] = *(const bf16x8*)(Ac + arow + mi * 2048 + a_k1);
    }
    __builtin_amdgcn_s_setprio(1);
#pragma unroll
    for (int mi = 0; mi < 4; ++mi)
#pragma unroll
      for (int ni = 0; ni < 4; ++ni) {
        acc[mi][ni] = MFMA16(af0[mi], bf0[ni], acc[mi][ni]);
        acc[mi][ni] = MFMA16(af1[mi], bf1[ni], acc[mi][ni]);
      }
    __builtin_amdgcn_s_setprio(0);

    cur = (cur == lds + 2 * BUFB) ? lds : cur + BUFB;
    stg = (stg == lds + 2 * BUFB) ? lds : stg + BUFB;
  }
  // drain stray (clamped) stage loads before workgroup exit (LDS dealloc!).
  asm volatile("s_waitcnt vmcnt(0)" ::: "memory");
}

// ---------------- fused QKV projection + RoPE epilogue ----------------
#define QSCALE 0.1803368801f
#define L2B 0.4152410118f  // log2(10000)/32
__global__ __launch_bounds__(512, 2) void gemm_qkv(const bf16* __restrict__ A,
                                                   const bf16* __restrict__ Wq,
                                                   const bf16* __restrict__ Wk,
                                                   const bf16* __restrict__ Wv,
                                                   bf16* __restrict__ Qb,
                                                   bf16* __restrict__ Kb,
                                                   bf16* __restrict__ Vt) {
  __shared__ __align__(16) char lds[3 * 49152];  // 144 KB -> 1 WG/CU
  const int tileM = blockIdx.x * 256;
  const int n0 = blockIdx.y * 128;
  // mode boundaries (2048, 2560) are 128-aligned so each tile is pure-mode.
  const bf16* Wp;
  int mode;
  if (n0 < HID) { Wp = Wq + (size_t)n0 * HID; mode = 0; }
  else if (n0 < HID + 512) { Wp = Wk + (size_t)(n0 - HID) * HID; mode = 1; }
  else { Wp = Wv + (size_t)(n0 - HID - 512) * HID; mode = 2; }

  f32x4 acc[4][4];
#pragma unroll
  for (int i = 0; i < 4; ++i)
#pragma unroll
    for (int j = 0; j < 4; ++j) acc[i][j] = (f32x4){0.f, 0.f, 0.f, 0.f};

  gemm_core_k64((const char*)(A + (size_t)tileM * HID), (const char*)Wp, lds, acc);

  const int tid = threadIdx.x;
  const int w = tid >> 6, lane = tid & 63;
  const int l16 = lane & 15, quad = lane >> 4;
  const int wr = w >> 1, wc = w & 1;
  const int mbase = tileM + wr * 64;
  const int cb = n0 + wc * 64;  // 64-aligned -> wave col span = one head

  if (mode == 2) {
    // V: transposed layout [b,kvh,d,s]
#pragma unroll
    for (int mi = 0; mi < 4; ++mi)
#pragma unroll
      for (int ni = 0; ni < 4; ++ni)
#pragma unroll
        for (int r = 0; r < 4; ++r) {
          int grow = mbase + mi * 16 + quad * 4 + r;
          int b = grow >> 11, spos = grow & (SS - 1);
          int nv = cb + ni * 16 + l16 - (HID + 512);
          Vt[(((size_t)(b * NKV + (nv >> 6))) * HD + (nv & 63)) * SS + spos] =
              (bf16)acc[mi][ni][r];
        }
  } else {
    // Q or K: RoPE in fp32 regs; pairs (ni=0,ni=2) at freq l16, (1,3) at l16+16.
    const float inv0 = __builtin_amdgcn_exp2f(-(float)l16 * L2B);
    const float inv1 = __builtin_amdgcn_exp2f(-(float)(l16 + 16) * L2B);
#pragma unroll
    for (int mi = 0; mi < 4; ++mi) {
#pragma unroll
      for (int r = 0; r < 4; ++r) {
        int grow = mbase + mi * 16 + quad * 4 + r;
        int b = grow >> 11, spos = grow & (SS - 1);
        float sn0, cs0, sn1, cs1;
        sincosf((float)spos * inv0, &sn0, &cs0);
        sincosf((float)spos * inv1, &sn1, &cs1);
        float a0 = acc[mi][0][r], a1 = acc[mi][1][r];
        float a2 = acc[mi][2][r], a3 = acc[mi][3][r];
        float o0 = a0 * cs0 - a2 * sn0;
        float o2 = a2 * cs0 + a0 * sn0;
        float o1 = a1 * cs1 - a3 * sn1;
        float o3 = a3 * cs1 + a1 * sn1;
        if (mode == 0) {
          bf16* qp = Qb + (size_t)grow * HID + cb + l16;
          qp[0]  = (bf16)(o0 * QSCALE);
          qp[16] = (bf16)(o1 * QSCALE);
          qp[32] = (bf16)(o2 * QSCALE);
          qp[48] = (bf16)(o3 * QSCALE);
        } else {
          int kvh = (cb - HID) >> 6;
          bf16* kp = Kb + ((size_t)(b * NKV + kvh) * SS + spos) * HD + l16;
          kp[0]  = (bf16)o0;
          kp[16] = (bf16)o1;
          kp[32] = (bf16)o2;
          kp[48] = (bf16)o3;
        }
      }
    }
  }
}

// ---------------- output projection (grid 16x16 = 256 blocks = 1/CU, 100% fill) ----------------
__global__ __launch_bounds__(512, 2) void gemm_out(const bf16* __restrict__ A,
                                                   const bf16* __restrict__ Wo,
                                                   float* __restrict__ out) {
  __shared__ __align__(16) char lds[3 * 49152];
  const int tileM = blockIdx.x * 256;
  const int n0 = blockIdx.y * 128;
  f32x4 acc[4][4];
#pragma unroll
  for (int i = 0; i < 4; ++i)
#pragma unroll
    for (int j = 0; j < 4; ++j) acc[i][j] = (f32x4){0.f, 0.f, 0.f, 0.f};

  gemm_core_k64((const char*)(A + (size_t)tileM * HID),
                (const char*)(Wo + (size_t)n0 * HID), lds, acc);

  const int tid = threadIdx.x;
  const int w = tid >> 6, lane = tid & 63;
  const int l16 = lane & 15, quad = lane >> 4;
  const int wr = w >> 1, wc = w & 1;
#pragma unroll
  for (int mi = 0; mi < 4; ++mi)
#pragma unroll
    for (int ni = 0; ni < 4; ++ni)
#pragma unroll
      for (int r = 0; r < 4; ++r) {
        int grow = tileM + wr * 64 + mi * 16 + quad * 4 + r;
        int gcol = n0 + wc * 64 + ni * 16 + l16;
        out[(size_t)grow * HID + gcol] = acc[mi][ni][r];
      }
}

// ---------------- flash attention v6: 128 q-rows per block (2 subtiles) ----------------
// (verified round 5; unchanged)
#define PSTR 72
__global__ __launch_bounds__(256, 3) void attn(const bf16* __restrict__ Qb,
                                               const bf16* __restrict__ Kb,
                                               const bf16* __restrict__ Vt,
                                               bf16* __restrict__ Ctx) {
  __shared__ bf16 Ktile[2][64 * 64];
  __shared__ bf16 Vtile[2][64 * 64];
  __shared__ bf16 Pbuf[4][32 * PSTR];   // per wave: rows 0-15 = A, 16-31 = B
  const int tid = threadIdx.x;
  const int w = tid >> 6, lane = tid & 63;
  const int l16 = lane & 15, quad = lane >> 4;
  const int bh = blockIdx.y, b = bh >> 5, h = bh & 31, kvh = h >> 2;
  bf16* Pw = &Pbuf[w][0];
  const char* Kslice = (const char*)(Kb + ((size_t)(b * NKV + kvh)) * SS * HD);
  const char* Vslice = (const char*)(Vt + ((size_t)(b * NKV + kvh)) * HD * SS);
  const int qrel = w * 16 + l16;        // 0..63 within each 64-row subtile

  const int srow = (lane >> 3) & 7;
  const int pchunk = ((lane & 7) ^ srow) << 4;
  const int so = ((quad ^ (l16 & 7)) << 4);
  const int so2 = so ^ 64;

  const int xA = (int)blockIdx.x;       // 0..7

  int cur = 0;
  // stage the very first K/V tile (kt=0)
  {
#pragma unroll
    for (int i = 0; i < 2; ++i) {
      const int r = w * 16 + i * 8 + srow;
      load_lds16(Kslice + (size_t)r * 128 + pchunk,
                 (char*)Ktile[0] + (w * 16 + i * 8) * 128);
      load_lds16(Vslice + (size_t)r * 4096 + pchunk,
                 (char*)Vtile[0] + (w * 16 + i * 8) * 128);
    }
  }

  for (int t = 0; t < 2; ++t) {
    const int X = t ? (15 - xA) : xA;   // 128-row superblock index
    const int qA = X * 128 + qrel;
    const int ktmax = 2 * X + 1;        // last kv tile (64 keys each)

    const bf16* QpA = Qb + ((size_t)(b * SS + qA)) * HID + h * HD + quad * 8;
    bf16x8 qa0 = *(const bf16x8*)QpA;
    bf16x8 qa1 = *(const bf16x8*)(QpA + 32);
    const bf16* QpB = QpA + (size_t)64 * HID;
    bf16x8 qbB0 = *(const bf16x8*)QpB;
    bf16x8 qbB1 = *(const bf16x8*)(QpB + 32);

    float lA = 0.f, lB = 0.f;
    f32x4 oA[4], oB[4];
#pragma unroll
    for (int d = 0; d < 4; ++d) {
      oA[d] = (f32x4){0.f, 0.f, 0.f, 0.f};
      oB[d] = (f32x4){0.f, 0.f, 0.f, 0.f};
    }

    for (int kt = 0; kt <= ktmax; ++kt) {
      __syncthreads();   // cur tile ready (staged a full compute phase ago)

      const bool have_next = (kt < ktmax) || (t == 0);
      if (have_next) {
        const int nkb = (kt < ktmax) ? (kt + 1) * 64 : 0;  // last: tile 0 for pass 1
        const int nb = cur ^ 1;
#pragma unroll
        for (int i = 0; i < 2; ++i) {
          const int r = w * 16 + i * 8 + srow;
          load_lds16(Kslice + (size_t)(nkb + r) * 128 + pchunk,
                     (char*)Ktile[nb] + (w * 16 + i * 8) * 128);
          load_lds16(Vslice + (size_t)r * 4096 + (size_t)nkb * 2 + pchunk,
                     (char*)Vtile[nb] + (w * 16 + i * 8) * 128);
        }
      }

      const char* Kc = (const char*)Ktile[cur] + l16 * 128;
      const char* Vc = (const char*)Vtile[cur] + l16 * 128;
      const bool skipA = (kt == ktmax);       // A fully masked on last tile
      const bool diagA = (kt == ktmax - 1);   // kt == 2X
      const bool diagB = (kt == ktmax);       // kt == 2X+1

      // QK^T + streaming no-max exp2 softmax for both subtiles; kf shared.
#pragma unroll
      for (int nt = 0; nt < 4; ++nt) {
        bf16x8 kf0 = *(const bf16x8*)(Kc + nt * 2048 + so);
        bf16x8 kf1 = *(const bf16x8*)(Kc + nt * 2048 + so2);
        const int krel = nt * 16 + quad * 4;

        bf16x4 pkA;
        if (skipA) {
          pkA[0] = (bf16)0.f; pkA[1] = (bf16)0.f;
          pkA[2] = (bf16)0.f; pkA[3] = (bf16)0.f;
        } else {
          f32x4 s = {0.f, 0.f, 0.f, 0.f};
          s = MFMA16(kf0, qa0, s);   // S^T: row = key, col = q (l16)
          s = MFMA16(kf1, qa1, s);
          if (diagA) {
#pragma unroll
            for (int r = 0; r < 4; ++r) {
              float p = (krel + r > qrel) ? 0.f : __builtin_amdgcn_exp2f(s[r]);
              lA += p;
              pkA[r] = (bf16)p;
            }
          } else {
#pragma unroll
            for (int r = 0; r < 4; ++r) {
              float p = __builtin_amdgcn_exp2f(s[r]);
              lA += p;
              pkA[r] = (bf16)p;
            }
          }
        }
        *(bf16x4*)&Pw[l16 * PSTR + krel] = pkA;

        f32x4 sB = {0.f, 0.f, 0.f, 0.f};
        sB = MFMA16(kf0, qbB0, sB);
        sB = MFMA16(kf1, qbB1, sB);
        bf16x4 pkB;
        if (diagB) {
#pragma unroll
          for (int r = 0; r < 4; ++r) {
            float p = (krel + r > qrel) ? 0.f : __builtin_amdgcn_exp2f(sB[r]);
            lB += p;
            pkB[r] = (bf16)p;
          }
        } else {
#pragma unroll
          for (int r = 0; r < 4; ++r) {
            float p = __builtin_amdgcn_exp2f(sB[r]);
            lB += p;
            pkB[r] = (bf16)p;
          }
        }
        *(bf16x4*)&Pw[(16 + l16) * PSTR + krel] = pkB;
      }

      // P back as B-operand fragments (per-wave buffer, no barrier needed)
      bf16x8 pA0 = *(const bf16x8*)&Pw[l16 * PSTR + quad * 8];
      bf16x8 pA1 = *(const bf16x8*)&Pw[l16 * PSTR + 32 + quad * 8];
      bf16x8 pB0 = *(const bf16x8*)&Pw[(16 + l16) * PSTR + quad * 8];
      bf16x8 pB1 = *(const bf16x8*)&Pw[(16 + l16) * PSTR + 32 + quad * 8];
#pragma unroll
      for (int dn = 0; dn < 4; ++dn) {
        bf16x8 v0 = *(const bf16x8*)(Vc + dn * 2048 + so);
        bf16x8 v1 = *(const bf16x8*)(Vc + dn * 2048 + so2);
        oA[dn] = MFMA16(v0, pA0, oA[dn]);  // O^T: row = d, col = q
        oA[dn] = MFMA16(v1, pA1, oA[dn]);
        oB[dn] = MFMA16(v0, pB0, oB[dn]);
        oB[dn] = MFMA16(v1, pB1, oB[dn]);
      }
      cur ^= 1;
    }

    lA += __shfl_xor(lA, 16);
    lA += __shfl_xor(lA, 32);
    lB += __shfl_xor(lB, 16);
    lB += __shfl_xor(lB, 32);
    const float invA = 1.0f / lA;
    const float invB = 1.0f / lB;
    bf16* CpA = Ctx + ((size_t)(b * SS + qA)) * HID + h * HD + quad * 4;
    bf16* CpB = CpA + (size_t)64 * HID;
#pragma unroll
    for (int dn = 0; dn < 4; ++dn) {
      bf16x4 ovA, ovB;
#pragma unroll
      for (int r = 0; r < 4; ++r) {
        ovA[r] = (bf16)(oA[dn][r] * invA);
        ovB[r] = (bf16)(oB[dn][r] * invB);
      }
      *(bf16x4*)(CpA + dn * 16) = ovA;
      *(bf16x4*)(CpB + dn * 16) = ovB;
    }
  }
}

// ---------------- launch ----------------
extern "C" void kernel_launch(void* const* d_in, const int* in_sizes, int n_in,
                              void* d_out, int out_size, void* d_ws, size_t ws_size,
                              hipStream_t stream) {
  const float* hs = (const float*)d_in[0];
  const float* Wq = (const float*)d_in[2];
  const float* Wk = (const float*)d_in[3];
  const float* Wv = (const float*)d_in[4];
  const float* Wo = (const float*)d_in[5];

  char* ws = (char*)d_ws;
  bf16* A_b  = (bf16*)(ws);              // 16 MB ; reused as Ctx after QKV gemm
  bf16* Wq_b = (bf16*)(ws + 16777216);   // 8 MB
  bf16* Wk_b = (bf16*)(ws + 25165824);   // 2 MB
  bf16* Wv_b = (bf16*)(ws + 27262976);   // 2 MB
  bf16* Wo_b = (bf16*)(ws + 29360128);   // 8 MB
  bf16* Qb   = (bf16*)(ws + 37748736);   // 16 MB
  bf16* Kb   = (bf16*)(ws + 54525952);   // 4 MB
  bf16* Vt   = (bf16*)(ws + 58720256);   // 4 MB  (end: 62914560)
  bf16* Ctx  = A_b;

  cvt_all<<<18432, 256, 0, stream>>>(hs, Wq, Wk, Wv, Wo, A_b, Wq_b, Wk_b, Wv_b, Wo_b);
  gemm_qkv<<<dim3(MTOT / 256, 24), 512, 0, stream>>>(A_b, Wq_b, Wk_b, Wv_b, Qb, Kb, Vt);
  attn<<<dim3(8, BB * NH), 256, 0, stream>>>(Qb, Kb, Vt, Ctx);
  gemm_out<<<dim3(MTOT / 256, HID / 128), 512, 0, stream>>>(Ctx, Wo_b, (float*)d_out);
}